// Round 12
// baseline (176.529 us; speedup 1.0000x reference)
//
#include <hip/hip_runtime.h>
#include <stdint.h>

typedef __attribute__((ext_vector_type(8))) short s8v;
typedef __attribute__((ext_vector_type(4))) short s4v;
typedef __attribute__((ext_vector_type(4))) float f4v;
typedef __attribute__((ext_vector_type(4))) unsigned short us4v;
typedef __attribute__((ext_vector_type(4))) float f32x4v;

#define DEV static __device__ __forceinline__

#define L2E 1.44269504f

DEV unsigned short f2bf(float f){
  uint32_t x = __builtin_bit_cast(uint32_t, f);
  uint32_t r = x + 0x7fffu + ((x >> 16) & 1u);
  return (unsigned short)(r >> 16);
}

DEV float exp2g(float x){
#if __has_builtin(__builtin_amdgcn_exp2f)
  return __builtin_amdgcn_exp2f(x);
#else
  return exp2f(x);
#endif
}

// pack 4 f32 -> 4 bf16 (two v_cvt_pk_bf16_f32, RNE — same as f2bf)
DEV s4v pack4(float a, float b, float c, float d){
  uint32_t r0, r1;
  asm("v_cvt_pk_bf16_f32 %0, %1, %2" : "=v"(r0) : "v"(a), "v"(b));
  asm("v_cvt_pk_bf16_f32 %0, %1, %2" : "=v"(r1) : "v"(c), "v"(d));
  union { uint32_t u[2]; s4v s; } u; u.u[0] = r0; u.u[1] = r1; return u.s;
}

DEV f4v mfma32(s8v a, s8v b, f4v c){
  return __builtin_amdgcn_mfma_f32_16x16x32_bf16(a, b, c, 0, 0, 0);
}
DEV f4v mfma16(s4v a, s4v b, f4v c){
  return __builtin_amdgcn_mfma_f32_16x16x16bf16_1k(a, b, c, 0, 0, 0);
}

DEV void load_lds16(const void* g, void* l){
  __builtin_amdgcn_global_load_lds((const __attribute__((address_space(1))) uint32_t*)g,
                                   (__attribute__((address_space(3))) uint32_t*)l, 16, 0, 0);
}

// ---------------- fused prep: xs concat + W transposes ----------------
__global__ __launch_bounds__(256) void k_prep(const float* __restrict__ x,
    const float* __restrict__ vp, const float* __restrict__ qw,
    const float* __restrict__ pw, unsigned short* __restrict__ xs,
    unsigned short* __restrict__ Wt, unsigned short* __restrict__ Pt){
  __shared__ float tile[32][33];
  const int bid = blockIdx.x;
  if (bid < 6192){
    int64_t e = ((int64_t)bid * 256 + threadIdx.x) * 4;
    int m = (int)(e / 768); int c = (int)(e % 768);
    int b = m / 1032, n = m % 1032;
    const float* src = (n < 8) ? (vp + ((int64_t)(b * 8 + n)) * 768 + c)
                               : (x  + ((int64_t)(b * 1024 + (n - 8))) * 768 + c);
    f32x4v v = *(const f32x4v*)src;
    us4v o = { f2bf(v[0]), f2bf(v[1]), f2bf(v[2]), f2bf(v[3]) };
    *(us4v*)(xs + e) = o;
    return;
  }
  const int wb = bid - 6192;
  const float* src; unsigned short* dst; int Cc, j0, k0;
  if (wb < 1728){
    int jt = wb % 72, kt = wb / 72;
    src = qw; dst = Wt; Cc = 2304; k0 = kt * 32; j0 = jt * 32;
  } else {
    int t2 = wb - 1728;
    int jt = t2 % 24, kt = t2 / 24;
    src = pw; dst = Pt; Cc = 768; k0 = kt * 32; j0 = jt * 32;
  }
  const int t = threadIdx.x;
  const int r = t >> 3, c4 = (t & 7) * 4;
  f32x4v v = *(const f32x4v*)(src + (int64_t)(k0 + r) * Cc + j0 + c4);
  tile[r][c4 + 0] = v[0]; tile[r][c4 + 1] = v[1];
  tile[r][c4 + 2] = v[2]; tile[r][c4 + 3] = v[3];
  __syncthreads();
  us4v o = { f2bf(tile[c4 + 0][r]), f2bf(tile[c4 + 1][r]),
             f2bf(tile[c4 + 2][r]), f2bf(tile[c4 + 3][r]) };
  *(us4v*)(dst + (int64_t)(j0 + r) * 768 + k0 + c4) = o;
}

// ---------------- GEMM: C = A[M,K] * Bt[N,K]^T + bias ----------------
// XCD-bijective block swizzle (m204): contiguous wgid runs per XCD for L2 reuse.
template<int MODE>
__global__ __launch_bounds__(256) void k_gemm(
    const unsigned short* __restrict__ A, const unsigned short* __restrict__ Bt,
    const float* __restrict__ bias, int M, int N, int K,
    unsigned short* __restrict__ qb, unsigned short* __restrict__ kb,
    unsigned short* __restrict__ vtb, float* __restrict__ outp)
{
  __shared__ __align__(16) unsigned short At [128 * 32];
  __shared__ __align__(16) unsigned short Btl[128 * 32];
  const int tid = threadIdx.x, lane = tid & 63, wid = tid >> 6;
  const int nbx = gridDim.x, nwg = nbx * gridDim.y;
  const int bid = blockIdx.y * nbx + blockIdx.x;
  const int xcd = bid & 7, idx = bid >> 3;
  const int q8 = nwg >> 3, r8 = nwg & 7;
  const int wgid = (xcd < r8 ? xcd * (q8 + 1) : r8 * (q8 + 1) + (xcd - r8) * q8) + idx;
  const int mbase = (wgid / nbx) * 128, nbase = (wgid % nbx) * 128;
  const int wr = wid >> 1, wc = wid & 1;
  const int g = lane >> 4, l15 = lane & 15;
  const int l2 = lane >> 2, l3 = lane & 3;
  f4v acc[4][4] = {};

  int srow0 = wid * 16 + l2;
  int srow1 = 64 + wid * 16 + l2;
  int sg0 = l3 ^ ((srow0 >> 1) & 3);
  int sg1 = l3 ^ ((srow1 >> 1) & 3);
  int arow0 = mbase + srow0; if (arow0 >= M) arow0 = 0;
  int arow1 = mbase + srow1; if (arow1 >= M) arow1 = 0;
  const unsigned short* a0 = A  + (int64_t)arow0 * K + sg0 * 8;
  const unsigned short* a1 = A  + (int64_t)arow1 * K + sg1 * 8;
  const unsigned short* b0 = Bt + (int64_t)(nbase + srow0) * K + sg0 * 8;
  const unsigned short* b1 = Bt + (int64_t)(nbase + srow1) * K + sg1 * 8;
  unsigned short* lA0 = At  + wid * 16 * 32;
  unsigned short* lA1 = At  + (64 + wid * 16) * 32;
  unsigned short* lB0 = Btl + wid * 16 * 32;
  unsigned short* lB1 = Btl + (64 + wid * 16) * 32;

  for (int ks = 0; ks < K; ks += 32){
    load_lds16(a0 + ks, lA0);
    load_lds16(a1 + ks, lA1);
    load_lds16(b0 + ks, lB0);
    load_lds16(b1 + ks, lB1);
    __syncthreads();
    s8v af[4], bf[4];
    #pragma unroll
    for (int mc = 0; mc < 4; mc++){
      int row = wr * 64 + mc * 16 + l15;
      int o = (row * 64 + g * 16) ^ (((row >> 1) & 3) << 4);
      af[mc] = *(const s8v*)((const char*)At + o);
    }
    #pragma unroll
    for (int nc = 0; nc < 4; nc++){
      int row = wc * 64 + nc * 16 + l15;
      int o = (row * 64 + g * 16) ^ (((row >> 1) & 3) << 4);
      bf[nc] = *(const s8v*)((const char*)Btl + o);
    }
    #pragma unroll
    for (int mc = 0; mc < 4; mc++)
      #pragma unroll
      for (int nc = 0; nc < 4; nc++)
        acc[mc][nc] = mfma32(af[mc], bf[nc], acc[mc][nc]);
    __syncthreads();
  }

  if (MODE == 0){
    const int which = nbase / 768;
    const int head  = ((nbase % 768) >> 6) + wc;
    #pragma unroll
    for (int nc = 0; nc < 4; nc++){
      int j = nbase + wc * 64 + nc * 16 + l15;
      float bv = bias[j];
      int d = nc * 16 + l15;
      #pragma unroll
      for (int mc = 0; mc < 4; mc++){
        int m0 = mbase + wr * 64 + mc * 16 + g * 4;
        if (m0 >= M) continue;
        int b = m0 / 1032, n = m0 % 1032;
        int bh = b * 12 + head;
        if (which == 2){
          us4v pk = { f2bf(acc[mc][nc][0] + bv), f2bf(acc[mc][nc][1] + bv),
                      f2bf(acc[mc][nc][2] + bv), f2bf(acc[mc][nc][3] + bv) };
          *(us4v*)(vtb + ((int64_t)bh * 64 + d) * 1032 + n) = pk;
        } else {
          unsigned short* dst = (which == 0 ? qb : kb) + ((int64_t)bh * 1032 + n) * 64 + d;
          #pragma unroll
          for (int r = 0; r < 4; r++) dst[(int64_t)r * 64] = f2bf(acc[mc][nc][r] + bv);
        }
      }
    }
  } else {
    #pragma unroll
    for (int nc = 0; nc < 4; nc++){
      int j = nbase + wc * 64 + nc * 16 + l15;
      float bv = bias[j];
      #pragma unroll
      for (int mc = 0; mc < 4; mc++){
        int m0 = mbase + wr * 64 + mc * 16 + g * 4;
        if (m0 >= M) continue;
        int b = m0 / 1032, n0 = m0 % 1032;
        #pragma unroll
        for (int r = 0; r < 4; r++){
          int n = n0 + r;
          float v = acc[mc][nc][r] + bv;
          int64_t dst = (n < 8) ? (6291456LL + ((int64_t)(b * 8 + n)) * 768 + j)
                                : (((int64_t)(b * 1024 + (n - 8))) * 768 + j);
          outp[dst] = v;
        }
      }
    }
  }
}

// ---------------- fused rel_h + rel_w (math verbatim r7) ----------------
__global__ __launch_bounds__(64) void k_rel(const unsigned short* __restrict__ qbuf,
    const float* __restrict__ rph, const float* __restrict__ rpw,
    float* __restrict__ relh, float* __restrict__ relw)
{
  const int lane = threadIdx.x;
  const int g = lane >> 4, l15 = lane & 15;
  if (blockIdx.x < 3072){
    const int bh = blockIdx.x >> 5;
    const int qh = blockIdx.x & 31;
    s8v qf[2][2];
    #pragma unroll
    for (int qc = 0; qc < 2; qc++){
      int n = qh * 32 + qc * 16 + l15 + 8;
      #pragma unroll
      for (int ch = 0; ch < 2; ch++)
        qf[qc][ch] = *(const s8v*)(qbuf + ((int64_t)bh * 1032 + n) * 64 + ch * 32 + g * 8);
    }
    s8v rf[2][2];
    #pragma unroll
    for (int kc = 0; kc < 2; kc++){
      int kh = kc * 16 + l15;
      #pragma unroll
      for (int ch = 0; ch < 2; ch++){
        const float* rp = rph + (int64_t)(qh - kh + 31) * 64 + ch * 32 + g * 8;
        f32x4v v0 = *(const f32x4v*)rp;
        f32x4v v1 = *(const f32x4v*)(rp + 4);
        s8v t = { (short)f2bf(v0[0]), (short)f2bf(v0[1]), (short)f2bf(v0[2]), (short)f2bf(v0[3]),
                  (short)f2bf(v1[0]), (short)f2bf(v1[1]), (short)f2bf(v1[2]), (short)f2bf(v1[3]) };
        rf[kc][ch] = t;
      }
    }
    #pragma unroll
    for (int kc = 0; kc < 2; kc++)
      #pragma unroll
      for (int qc = 0; qc < 2; qc++){
        f4v d = {0.f, 0.f, 0.f, 0.f};
        d = mfma32(rf[kc][0], qf[qc][0], d);
        d = mfma32(rf[kc][1], qf[qc][1], d);
        #pragma unroll
        for (int r = 0; r < 4; r++)
          relh[((int64_t)bh * 32 + kc * 16 + g * 4 + r) * 1024 + qh * 32 + qc * 16 + l15] = d[r] * L2E;
      }
  } else {
    const int bid = blockIdx.x - 3072;
    const int bh = bid >> 5;
    const int qw = bid & 31;
    s8v qf[2][2];
    #pragma unroll
    for (int qc = 0; qc < 2; qc++){
      int qp = qw + 32 * (qc * 16 + l15);
      int n = qp + 8;
      #pragma unroll
      for (int ch = 0; ch < 2; ch++)
        qf[qc][ch] = *(const s8v*)(qbuf + ((int64_t)bh * 1032 + n) * 64 + ch * 32 + g * 8);
    }
    s8v wf[2][2];
    #pragma unroll
    for (int kc = 0; kc < 2; kc++){
      int kw = kc * 16 + l15;
      #pragma unroll
      for (int ch = 0; ch < 2; ch++){
        const float* rp = rpw + (int64_t)(qw - kw + 31) * 64 + ch * 32 + g * 8;
        f32x4v v0 = *(const f32x4v*)rp;
        f32x4v v1 = *(const f32x4v*)(rp + 4);
        s8v t = { (short)f2bf(v0[0]), (short)f2bf(v0[1]), (short)f2bf(v0[2]), (short)f2bf(v0[3]),
                  (short)f2bf(v1[0]), (short)f2bf(v1[1]), (short)f2bf(v1[2]), (short)f2bf(v1[3]) };
        wf[kc][ch] = t;
      }
    }
    #pragma unroll
    for (int qc = 0; qc < 2; qc++)
      #pragma unroll
      for (int kc = 0; kc < 2; kc++){
        f4v d = {0.f, 0.f, 0.f, 0.f};
        d = mfma32(qf[qc][0], wf[kc][0], d);
        d = mfma32(qf[qc][1], wf[kc][1], d);
        #pragma unroll
        for (int r = 0; r < 4; r++){
          int qp = qw + 32 * (qc * 16 + g * 4 + r);
          relw[((int64_t)bh * 1024 + qp) * 32 + kc * 16 + l15] = d[r] * L2E;
        }
      }
  }
}

// ---------------- flash attention: 8 waves = 4 q-tiles x 2 K-halves ----------------
// Per half h: its own single-buffered K/V LDS pair, staged by its 4 waves with the
// EXACT r7 geometry and interval shape (2 loads/wave -> barrier -> compute ->
// barrier). Halves cover kt [0,17) and [17,33); linear LDS merge at the end
// (max-free softmax => O = O0+O1, l = l0+l1). Doubles waves/CU vs r7.
__global__ __launch_bounds__(512, 4) void k_attn(
    const unsigned short* __restrict__ qb, const unsigned short* __restrict__ kb,
    const unsigned short* __restrict__ vtb, const float* __restrict__ relh,
    const float* __restrict__ relw, unsigned short* __restrict__ ao)
{
  const int lane = threadIdx.x & 63, wid = threadIdx.x >> 6;
  const int qtl = wid & 3, h = wid >> 2;
  // XCD-bijective swizzle: 864 = 8 * 108
  const int wq = (blockIdx.x & 7) * 108 + (blockIdx.x >> 3);
  const int bh = wq / 9;
  const int qg = wq % 9;
  int qt = qg * 4 + qtl; if (qt > 32) qt = 32;   // dup waves write identical data
  const int qbase = qt * 32;
  const int g = lane >> 4, l15 = lane & 15;
  const int b = bh / 12, head = bh % 12;
  const float C1 = 0.125f * L2E;
  const float NEG = -144.269504f;   // exp2 -> 0

  __shared__ __align__(16) unsigned short Kl[2][32 * 64];  // per-half K tile, 4KB each
  __shared__ __align__(16) unsigned short Vl[2][64 * 32];  // per-half V tile, 4KB each
  __shared__ __align__(16) float ofs[4][4][2][64][4];      // 32KB: h=1 O-partials
  __shared__ float lsh[4][2][64];                          // 2KB:  h=1 l-partials

  f4v of[4][2] = {};
  float lrun[2] = {0.f, 0.f};
  int qn_[2], qp_[2];

  s8v qf[2][2];
  float rw[2][2][4];
  #pragma unroll
  for (int qc = 0; qc < 2; qc++){
    int qn = qbase + qc * 16 + l15;
    qn_[qc] = qn;
    int qcl = qn < 1032 ? qn : 1031;
    #pragma unroll
    for (int ch = 0; ch < 2; ch++)
      qf[qc][ch] = *(const s8v*)(qb + ((int64_t)bh * 1032 + qcl) * 64 + ch * 32 + g * 8);
    int qp = qn - 8; if (qp < 0) qp = 0; if (qp > 1023) qp = 1023;
    qp_[qc] = qp;
  }
  #pragma unroll
  for (int qc = 0; qc < 2; qc++)
    #pragma unroll
    for (int kc = 0; kc < 2; kc++)
      #pragma unroll
      for (int r = 0; r < 4; r++){
        int kw = (kc * 16 + g * 4 + r + 24) & 31;
        rw[qc][kc][r] = relw[((int64_t)bh * 1024 + qp_[qc]) * 32 + kw];
      }

  const char* kbb = (const char*)(kb + (int64_t)bh * 1032 * 64);
  const char* vbb = (const char*)(vtb + (int64_t)bh * 64 * 1032);
  const float* rhbase = relh + (int64_t)bh * 32 * 1024;

  // staging geometry (r7-verbatim, with qtl as the within-half wave index)
  const int krow_l = (lane >> 3);                    // 0..7 within wave's 8 rows
  const int kcol_s = ((lane & 7) ^ krow_l) << 4;     // pre-swizzled col byte
  const int vd_l   = (lane >> 2);                    // 0..15 within wave's 16 rows
  const int vslot  = ((lane & 3) ^ ((lane >> 2) ^ (lane >> 4)) & 3);
  char* kdst = (char*)Kl[h] + qtl * 1024;
  char* vdst = (char*)Vl[h] + qtl * 1024;
  const int vsw = (l15 ^ (l15 >> 2)) & 3;            // read-side V swizzle

  const int ktbase = h ? 17 : 0;
  const int ntile  = h ? 16 : 17;

  for (int i = 0; i < 17; i++){
    const bool act = (i < ntile);        // wave-uniform
    const int kt = ktbase + i;
    // ---- stage this half's tile (r7-verbatim quota: 2 loads/wave) ----
    if (act){
      int gr = kt * 32 + qtl * 8 + krow_l; if (gr > 1031) gr = 1031;
      load_lds16(kbb + (int64_t)gr * 128 + kcol_s, kdst);
      int d = qtl * 16 + vd_l;
      int scol = kt * 64 + (vslot << 4); if (scol > 2048) scol = 2048;
      load_lds16(vbb + (int64_t)d * 2064 + scol, vdst);
    }
    __syncthreads();

    if (act){
      // ---- fragments from this half's LDS ----
      const char* Kc = (const char*)Kl[h];
      const char* Vc = (const char*)Vl[h];
      s8v kf[2][2];
      #pragma unroll
      for (int kc = 0; kc < 2; kc++){
        int roff = (kc * 16 + l15) << 7;
        #pragma unroll
        for (int ch = 0; ch < 2; ch++)
          kf[kc][ch] = *(const s8v*)(Kc + roff + ((((ch << 2) + g) ^ (l15 & 7)) << 4));
      }
      s4v vf[4][2];
      #pragma unroll
      for (int dc = 0; dc < 4; dc++){
        int doff = ((dc * 16 + l15) << 6) + ((g & 1) << 3);
        #pragma unroll
        for (int kc = 0; kc < 2; kc++)
          vf[dc][kc] = *(const s4v*)(Vc + doff + ((((kc << 1) + (g >> 1)) ^ vsw) << 4));
      }
      // rel_h rows
      int khA = kt - 1; if (khA < 0) khA = 0;
      int khB = kt; if (khB > 31) khB = 31;
      float rhA[2], rhB[2];
      #pragma unroll
      for (int qc = 0; qc < 2; qc++){
        rhA[qc] = rhbase[(int64_t)khA * 1024 + qp_[qc]];
        rhB[qc] = rhbase[(int64_t)khB * 1024 + qp_[qc]];
      }
      // QK^T (swapped: lane col = query)
      f4v sv[2][2];
      #pragma unroll
      for (int qc = 0; qc < 2; qc++)
        #pragma unroll
        for (int kc = 0; kc < 2; kc++){
          f4v s = {0.f, 0.f, 0.f, 0.f};
          s = mfma32(kf[kc][0], qf[qc][0], s);
          s = mfma32(kf[kc][1], qf[qc][1], s);
          sv[qc][kc] = s;
        }
      const bool anyprompt = (kt == 0);
      const bool anymask = (kt == 32);
      s4v bp[2][2];
      #pragma unroll
      for (int qc = 0; qc < 2; qc++){
        const bool qpr = qn_[qc] < 8;
        float p[8];
        #pragma unroll
        for (int kc = 0; kc < 2; kc++)
          #pragma unroll
          for (int r = 0; r < 4; r++){
            int off = kc * 16 + g * 4 + r;
            float bias = qpr ? 0.f : ((off >= 8 ? rhB[qc] : rhA[qc]) + rw[qc][kc][r]);
            if (anyprompt && off < 8 && !qpr) bias = NEG;
            float L = fmaf(sv[qc][kc][r], C1, bias);
            if (anymask && off >= 8) L = NEG;
            p[kc * 4 + r] = exp2g(L);
          }
        lrun[qc] += ((p[0]+p[1])+(p[2]+p[3])) + ((p[4]+p[5])+(p[6]+p[7]));
        bp[qc][0] = pack4(p[0], p[1], p[2], p[3]);
        bp[qc][1] = pack4(p[4], p[5], p[6], p[7]);
      }
      // PV
      #pragma unroll
      for (int dc = 0; dc < 4; dc++)
        #pragma unroll
        for (int kc = 0; kc < 2; kc++)
          #pragma unroll
          for (int qc = 0; qc < 2; qc++)
            of[dc][qc] = mfma16(vf[dc][kc], bp[qc][kc], of[dc][qc]);
    }

    __syncthreads();   // all waves done reading before next stage overwrites
  }

  // ---- merge halves: h=1 publishes, h=0 sums linearly, normalizes, stores ----
  if (h == 1){
    #pragma unroll
    for (int dc = 0; dc < 4; dc++)
      #pragma unroll
      for (int qc = 0; qc < 2; qc++)
        *(f4v*)&ofs[qtl][dc][qc][lane][0] = of[dc][qc];
    #pragma unroll
    for (int qc = 0; qc < 2; qc++)
      lsh[qtl][qc][lane] = lrun[qc];
  }
  __syncthreads();
  if (h == 0){
    #pragma unroll
    for (int qc = 0; qc < 2; qc++){
      int qn = qn_[qc];
      if (qn >= 1032) continue;
      float lt = lrun[qc] + lsh[qtl][qc][lane];
      lt += __shfl_xor(lt, 16);
      lt += __shfl_xor(lt, 32);
      float inv = 1.0f / lt;
      unsigned short* dst = ao + ((int64_t)(b * 1032 + qn)) * 768 + head * 64;
      #pragma unroll
      for (int dc = 0; dc < 4; dc++){
        f4v ot = of[dc][qc] + *(const f4v*)&ofs[qtl][dc][qc][lane][0];
        us4v pk = { f2bf(ot[0] * inv), f2bf(ot[1] * inv),
                    f2bf(ot[2] * inv), f2bf(ot[3] * inv) };
        *(us4v*)(dst + dc * 16 + g * 4) = pk;
      }
    }
  }
}

extern "C" void kernel_launch(void* const* d_in, const int* in_sizes, int n_in,
                              void* d_out, int out_size, void* d_ws, size_t ws_size,
                              hipStream_t stream)
{
  const float* x   = (const float*)d_in[0];
  const float* vp  = (const float*)d_in[1];
  const float* qw  = (const float*)d_in[2];
  const float* qbb = (const float*)d_in[3];
  const float* pw  = (const float*)d_in[4];
  const float* pb  = (const float*)d_in[5];
  const float* rph = (const float*)d_in[6];
  const float* rpw = (const float*)d_in[7];
  float* out = (float*)d_out;

  char* ws = (char*)d_ws;
  size_t off = 0;
  auto alloc = [&](size_t bytes) -> void* {
    void* p = ws + off;
    off = (off + bytes + 255) & ~(size_t)255;
    return p;
  };
  unsigned short* xs   = (unsigned short*)alloc((size_t)8256 * 768 * 2);
  unsigned short* Wt   = (unsigned short*)alloc((size_t)2304 * 768 * 2);
  unsigned short* Pt   = (unsigned short*)alloc((size_t)768 * 768 * 2);
  unsigned short* qbuf = (unsigned short*)alloc((size_t)96 * 1032 * 64 * 2);
  unsigned short* kbuf = (unsigned short*)alloc((size_t)96 * 1032 * 64 * 2 + 4096);
  unsigned short* vtb  = (unsigned short*)alloc((size_t)96 * 64 * 1032 * 2 + 4096);
  float* relh = (float*)alloc((size_t)96 * 32 * 1024 * 4);
  float* relw = (float*)alloc((size_t)96 * 1024 * 32 * 4);
  unsigned short* ao = xs;  // xs dead after QKV GEMM; reuse for attention output

  k_prep<<<8496, 256, 0, stream>>>(x, vp, qw, pw, xs, Wt, Pt);
  k_gemm<0><<<dim3(18, 65), 256, 0, stream>>>(xs, Wt, qbb, 8256, 2304, 768,
                                              qbuf, kbuf, vtb, nullptr);
  k_rel<<<6144, 64, 0, stream>>>(qbuf, rph, rpw, relh, relw);
  k_attn<<<864, 512, 0, stream>>>(qbuf, kbuf, vtb, relh, relw, ao);
  k_gemm<1><<<dim3(6, 65), 256, 0, stream>>>(ao, Pt, pb, 8256, 768, 768,
                                             nullptr, nullptr, nullptr, out);
}

// Round 14
// 164.846 us; speedup vs baseline: 1.0709x; 1.0709x over previous
//
#include <hip/hip_runtime.h>
#include <stdint.h>

typedef __attribute__((ext_vector_type(8))) short s8v;
typedef __attribute__((ext_vector_type(4))) short s4v;
typedef __attribute__((ext_vector_type(4))) float f4v;
typedef __attribute__((ext_vector_type(4))) unsigned short us4v;
typedef __attribute__((ext_vector_type(4))) float f32x4v;

#define DEV static __device__ __forceinline__

#define L2E 1.44269504f

DEV unsigned short f2bf(float f){
  uint32_t x = __builtin_bit_cast(uint32_t, f);
  uint32_t r = x + 0x7fffu + ((x >> 16) & 1u);
  return (unsigned short)(r >> 16);
}

DEV float exp2g(float x){
#if __has_builtin(__builtin_amdgcn_exp2f)
  return __builtin_amdgcn_exp2f(x);
#else
  return exp2f(x);
#endif
}

// pack 4 f32 -> 4 bf16 (two v_cvt_pk_bf16_f32, RNE — same as f2bf)
DEV s4v pack4(float a, float b, float c, float d){
  uint32_t r0, r1;
  asm("v_cvt_pk_bf16_f32 %0, %1, %2" : "=v"(r0) : "v"(a), "v"(b));
  asm("v_cvt_pk_bf16_f32 %0, %1, %2" : "=v"(r1) : "v"(c), "v"(d));
  union { uint32_t u[2]; s4v s; } u; u.u[0] = r0; u.u[1] = r1; return u.s;
}

DEV f4v mfma32(s8v a, s8v b, f4v c){
  return __builtin_amdgcn_mfma_f32_16x16x32_bf16(a, b, c, 0, 0, 0);
}
DEV f4v mfma16(s4v a, s4v b, f4v c){
  return __builtin_amdgcn_mfma_f32_16x16x16bf16_1k(a, b, c, 0, 0, 0);
}

DEV void load_lds16(const void* g, void* l){
  __builtin_amdgcn_global_load_lds((const __attribute__((address_space(1))) uint32_t*)g,
                                   (__attribute__((address_space(3))) uint32_t*)l, 16, 0, 0);
}

// ---------------- fused prep: xs concat + W transposes ----------------
__global__ __launch_bounds__(256) void k_prep(const float* __restrict__ x,
    const float* __restrict__ vp, const float* __restrict__ qw,
    const float* __restrict__ pw, unsigned short* __restrict__ xs,
    unsigned short* __restrict__ Wt, unsigned short* __restrict__ Pt){
  __shared__ float tile[32][33];
  const int bid = blockIdx.x;
  if (bid < 6192){
    int64_t e = ((int64_t)bid * 256 + threadIdx.x) * 4;
    int m = (int)(e / 768); int c = (int)(e % 768);
    int b = m / 1032, n = m % 1032;
    const float* src = (n < 8) ? (vp + ((int64_t)(b * 8 + n)) * 768 + c)
                               : (x  + ((int64_t)(b * 1024 + (n - 8))) * 768 + c);
    f32x4v v = *(const f32x4v*)src;
    us4v o = { f2bf(v[0]), f2bf(v[1]), f2bf(v[2]), f2bf(v[3]) };
    *(us4v*)(xs + e) = o;
    return;
  }
  const int wb = bid - 6192;
  const float* src; unsigned short* dst; int Cc, j0, k0;
  if (wb < 1728){
    int jt = wb % 72, kt = wb / 72;
    src = qw; dst = Wt; Cc = 2304; k0 = kt * 32; j0 = jt * 32;
  } else {
    int t2 = wb - 1728;
    int jt = t2 % 24, kt = t2 / 24;
    src = pw; dst = Pt; Cc = 768; k0 = kt * 32; j0 = jt * 32;
  }
  const int t = threadIdx.x;
  const int r = t >> 3, c4 = (t & 7) * 4;
  f32x4v v = *(const f32x4v*)(src + (int64_t)(k0 + r) * Cc + j0 + c4);
  tile[r][c4 + 0] = v[0]; tile[r][c4 + 1] = v[1];
  tile[r][c4 + 2] = v[2]; tile[r][c4 + 3] = v[3];
  __syncthreads();
  us4v o = { f2bf(tile[c4 + 0][r]), f2bf(tile[c4 + 1][r]),
             f2bf(tile[c4 + 2][r]), f2bf(tile[c4 + 3][r]) };
  *(us4v*)(dst + (int64_t)(j0 + r) * 768 + k0 + c4) = o;
}

// ---------------- GEMM: C = A[M,K] * Bt[N,K]^T + bias ----------------
// XCD-bijective block swizzle (m204) — verified correct + faster in round 12.
template<int MODE>
__global__ __launch_bounds__(256) void k_gemm(
    const unsigned short* __restrict__ A, const unsigned short* __restrict__ Bt,
    const float* __restrict__ bias, int M, int N, int K,
    unsigned short* __restrict__ qb, unsigned short* __restrict__ kb,
    unsigned short* __restrict__ vtb, float* __restrict__ outp)
{
  __shared__ __align__(16) unsigned short At [128 * 32];
  __shared__ __align__(16) unsigned short Btl[128 * 32];
  const int tid = threadIdx.x, lane = tid & 63, wid = tid >> 6;
  const int nbx = gridDim.x, nwg = nbx * gridDim.y;
  const int bid = blockIdx.y * nbx + blockIdx.x;
  const int xcd = bid & 7, idx = bid >> 3;
  const int q8 = nwg >> 3, r8 = nwg & 7;
  const int wgid = (xcd < r8 ? xcd * (q8 + 1) : r8 * (q8 + 1) + (xcd - r8) * q8) + idx;
  const int mbase = (wgid / nbx) * 128, nbase = (wgid % nbx) * 128;
  const int wr = wid >> 1, wc = wid & 1;
  const int g = lane >> 4, l15 = lane & 15;
  const int l2 = lane >> 2, l3 = lane & 3;
  f4v acc[4][4] = {};

  int srow0 = wid * 16 + l2;
  int srow1 = 64 + wid * 16 + l2;
  int sg0 = l3 ^ ((srow0 >> 1) & 3);
  int sg1 = l3 ^ ((srow1 >> 1) & 3);
  int arow0 = mbase + srow0; if (arow0 >= M) arow0 = 0;
  int arow1 = mbase + srow1; if (arow1 >= M) arow1 = 0;
  const unsigned short* a0 = A  + (int64_t)arow0 * K + sg0 * 8;
  const unsigned short* a1 = A  + (int64_t)arow1 * K + sg1 * 8;
  const unsigned short* b0 = Bt + (int64_t)(nbase + srow0) * K + sg0 * 8;
  const unsigned short* b1 = Bt + (int64_t)(nbase + srow1) * K + sg1 * 8;
  unsigned short* lA0 = At  + wid * 16 * 32;
  unsigned short* lA1 = At  + (64 + wid * 16) * 32;
  unsigned short* lB0 = Btl + wid * 16 * 32;
  unsigned short* lB1 = Btl + (64 + wid * 16) * 32;

  for (int ks = 0; ks < K; ks += 32){
    load_lds16(a0 + ks, lA0);
    load_lds16(a1 + ks, lA1);
    load_lds16(b0 + ks, lB0);
    load_lds16(b1 + ks, lB1);
    __syncthreads();
    s8v af[4], bf[4];
    #pragma unroll
    for (int mc = 0; mc < 4; mc++){
      int row = wr * 64 + mc * 16 + l15;
      int o = (row * 64 + g * 16) ^ (((row >> 1) & 3) << 4);
      af[mc] = *(const s8v*)((const char*)At + o);
    }
    #pragma unroll
    for (int nc = 0; nc < 4; nc++){
      int row = wc * 64 + nc * 16 + l15;
      int o = (row * 64 + g * 16) ^ (((row >> 1) & 3) << 4);
      bf[nc] = *(const s8v*)((const char*)Btl + o);
    }
    #pragma unroll
    for (int mc = 0; mc < 4; mc++)
      #pragma unroll
      for (int nc = 0; nc < 4; nc++)
        acc[mc][nc] = mfma32(af[mc], bf[nc], acc[mc][nc]);
    __syncthreads();
  }

  if (MODE == 0){
    const int which = nbase / 768;
    const int head  = ((nbase % 768) >> 6) + wc;
    #pragma unroll
    for (int nc = 0; nc < 4; nc++){
      int j = nbase + wc * 64 + nc * 16 + l15;
      float bv = bias[j];
      int d = nc * 16 + l15;
      #pragma unroll
      for (int mc = 0; mc < 4; mc++){
        int m0 = mbase + wr * 64 + mc * 16 + g * 4;
        if (m0 >= M) continue;
        int b = m0 / 1032, n = m0 % 1032;
        int bh = b * 12 + head;
        if (which == 2){
          us4v pk = { f2bf(acc[mc][nc][0] + bv), f2bf(acc[mc][nc][1] + bv),
                      f2bf(acc[mc][nc][2] + bv), f2bf(acc[mc][nc][3] + bv) };
          *(us4v*)(vtb + ((int64_t)bh * 64 + d) * 1032 + n) = pk;
        } else {
          unsigned short* dst = (which == 0 ? qb : kb) + ((int64_t)bh * 1032 + n) * 64 + d;
          #pragma unroll
          for (int r = 0; r < 4; r++) dst[(int64_t)r * 64] = f2bf(acc[mc][nc][r] + bv);
        }
      }
    }
  } else {
    #pragma unroll
    for (int nc = 0; nc < 4; nc++){
      int j = nbase + wc * 64 + nc * 16 + l15;
      float bv = bias[j];
      #pragma unroll
      for (int mc = 0; mc < 4; mc++){
        int m0 = mbase + wr * 64 + mc * 16 + g * 4;
        if (m0 >= M) continue;
        int b = m0 / 1032, n0 = m0 % 1032;
        #pragma unroll
        for (int r = 0; r < 4; r++){
          int n = n0 + r;
          float v = acc[mc][nc][r] + bv;
          int64_t dst = (n < 8) ? (6291456LL + ((int64_t)(b * 8 + n)) * 768 + j)
                                : (((int64_t)(b * 1024 + (n - 8))) * 768 + j);
          outp[dst] = v;
        }
      }
    }
  }
}

// ---------------- fused rel_h + rel_w (math verbatim r7) ----------------
__global__ __launch_bounds__(64) void k_rel(const unsigned short* __restrict__ qbuf,
    const float* __restrict__ rph, const float* __restrict__ rpw,
    float* __restrict__ relh, float* __restrict__ relw)
{
  const int lane = threadIdx.x;
  const int g = lane >> 4, l15 = lane & 15;
  if (blockIdx.x < 3072){
    const int bh = blockIdx.x >> 5;
    const int qh = blockIdx.x & 31;
    s8v qf[2][2];
    #pragma unroll
    for (int qc = 0; qc < 2; qc++){
      int n = qh * 32 + qc * 16 + l15 + 8;
      #pragma unroll
      for (int ch = 0; ch < 2; ch++)
        qf[qc][ch] = *(const s8v*)(qbuf + ((int64_t)bh * 1032 + n) * 64 + ch * 32 + g * 8);
    }
    s8v rf[2][2];
    #pragma unroll
    for (int kc = 0; kc < 2; kc++){
      int kh = kc * 16 + l15;
      #pragma unroll
      for (int ch = 0; ch < 2; ch++){
        const float* rp = rph + (int64_t)(qh - kh + 31) * 64 + ch * 32 + g * 8;
        f32x4v v0 = *(const f32x4v*)rp;
        f32x4v v1 = *(const f32x4v*)(rp + 4);
        s8v t = { (short)f2bf(v0[0]), (short)f2bf(v0[1]), (short)f2bf(v0[2]), (short)f2bf(v0[3]),
                  (short)f2bf(v1[0]), (short)f2bf(v1[1]), (short)f2bf(v1[2]), (short)f2bf(v1[3]) };
        rf[kc][ch] = t;
      }
    }
    #pragma unroll
    for (int kc = 0; kc < 2; kc++)
      #pragma unroll
      for (int qc = 0; qc < 2; qc++){
        f4v d = {0.f, 0.f, 0.f, 0.f};
        d = mfma32(rf[kc][0], qf[qc][0], d);
        d = mfma32(rf[kc][1], qf[qc][1], d);
        #pragma unroll
        for (int r = 0; r < 4; r++)
          relh[((int64_t)bh * 32 + kc * 16 + g * 4 + r) * 1024 + qh * 32 + qc * 16 + l15] = d[r] * L2E;
      }
  } else {
    const int bid = blockIdx.x - 3072;
    const int bh = bid >> 5;
    const int qw = bid & 31;
    s8v qf[2][2];
    #pragma unroll
    for (int qc = 0; qc < 2; qc++){
      int qp = qw + 32 * (qc * 16 + l15);
      int n = qp + 8;
      #pragma unroll
      for (int ch = 0; ch < 2; ch++)
        qf[qc][ch] = *(const s8v*)(qbuf + ((int64_t)bh * 1032 + n) * 64 + ch * 32 + g * 8);
    }
    s8v wf[2][2];
    #pragma unroll
    for (int kc = 0; kc < 2; kc++){
      int kw = kc * 16 + l15;
      #pragma unroll
      for (int ch = 0; ch < 2; ch++){
        const float* rp = rpw + (int64_t)(qw - kw + 31) * 64 + ch * 32 + g * 8;
        f32x4v v0 = *(const f32x4v*)rp;
        f32x4v v1 = *(const f32x4v*)(rp + 4);
        s8v t = { (short)f2bf(v0[0]), (short)f2bf(v0[1]), (short)f2bf(v0[2]), (short)f2bf(v0[3]),
                  (short)f2bf(v1[0]), (short)f2bf(v1[1]), (short)f2bf(v1[2]), (short)f2bf(v1[3]) };
        wf[kc][ch] = t;
      }
    }
    #pragma unroll
    for (int qc = 0; qc < 2; qc++)
      #pragma unroll
      for (int kc = 0; kc < 2; kc++){
        f4v d = {0.f, 0.f, 0.f, 0.f};
        d = mfma32(qf[qc][0], wf[kc][0], d);
        d = mfma32(qf[qc][1], wf[kc][1], d);
        #pragma unroll
        for (int r = 0; r < 4; r++){
          int qp = qw + 32 * (qc * 16 + g * 4 + r);
          relw[((int64_t)bh * 1024 + qp) * 32 + kc * 16 + l15] = d[r] * L2E;
        }
      }
  }
}

// ---------------- flash attention, LDS-staged K/V shared by 4 waves ----------------
// VERBATIM round-11 version (passed twice: r7 @70.3us, r11 @70.4us).
// FROZEN: no vmem op may be added to or moved across this loop's barriers —
// r8/r9/r10/r13 all raced/corrupted when the interval was perturbed.
__global__ __launch_bounds__(256, 3) void k_attn(
    const unsigned short* __restrict__ qb, const unsigned short* __restrict__ kb,
    const unsigned short* __restrict__ vtb, const float* __restrict__ relh,
    const float* __restrict__ relw, unsigned short* __restrict__ ao)
{
  const int lane = threadIdx.x & 63, wid = threadIdx.x >> 6;
  // XCD-bijective swizzle: 864 = 8 * 108
  const int wq = (blockIdx.x & 7) * 108 + (blockIdx.x >> 3);
  const int bh = wq / 9;
  const int qg = wq % 9;
  int qt = qg * 4 + wid; if (qt > 32) qt = 32;   // dup waves write identical data
  const int qbase = qt * 32;
  const int g = lane >> 4, l15 = lane & 15;
  const int b = bh / 12, head = bh % 12;
  const float C1 = 0.125f * L2E;
  const float NEG = -144.269504f;   // exp2 -> 0

  __shared__ __align__(16) unsigned short Kl[32 * 64];  // 4KB, row=128B, slot^=(r&7)
  __shared__ __align__(16) unsigned short Vl[64 * 32];  // 4KB, row=64B,  slot^=((d^(d>>2))&3)

  f4v of[4][2] = {};
  float lrun[2] = {0.f, 0.f};
  int qn_[2], qp_[2];

  s8v qf[2][2];
  float rw[2][2][4];
  #pragma unroll
  for (int qc = 0; qc < 2; qc++){
    int qn = qbase + qc * 16 + l15;
    qn_[qc] = qn;
    int qcl = qn < 1032 ? qn : 1031;
    #pragma unroll
    for (int ch = 0; ch < 2; ch++)
      qf[qc][ch] = *(const s8v*)(qb + ((int64_t)bh * 1032 + qcl) * 64 + ch * 32 + g * 8);
    int qp = qn - 8; if (qp < 0) qp = 0; if (qp > 1023) qp = 1023;
    qp_[qc] = qp;
  }
  #pragma unroll
  for (int qc = 0; qc < 2; qc++)
    #pragma unroll
    for (int kc = 0; kc < 2; kc++)
      #pragma unroll
      for (int r = 0; r < 4; r++){
        int kw = (kc * 16 + g * 4 + r + 24) & 31;
        rw[qc][kc][r] = relw[((int64_t)bh * 1024 + qp_[qc]) * 32 + kw];
      }

  const char* kbb = (const char*)(kb + (int64_t)bh * 1032 * 64);
  const char* vbb = (const char*)(vtb + (int64_t)bh * 64 * 1032);
  const float* rhbase = relh + (int64_t)bh * 32 * 1024;

  // staging geometry (per wave; lane's LDS dest = base + lane*16, HW-linear)
  const int krow_l = (lane >> 3);                    // 0..7 within wave's 8 rows
  const int kcol_s = ((lane & 7) ^ krow_l) << 4;     // pre-swizzled col byte
  const int vd_l   = (lane >> 2);                    // 0..15 within wave's 16 rows
  const int vslot  = ((lane & 3) ^ ((lane >> 2) ^ (lane >> 4)) & 3);
  char* kdst = (char*)Kl + wid * 1024;
  char* vdst = (char*)Vl + wid * 1024;
  const int vsw = (l15 ^ (l15 >> 2)) & 3;            // read-side V swizzle

  for (int kt = 0; kt < 33; kt++){
    // ---- stage tile kt (4 waves cooperatively; clamped sources stay finite) ----
    {
      int gr = kt * 32 + wid * 8 + krow_l; if (gr > 1031) gr = 1031;
      load_lds16(kbb + (int64_t)gr * 128 + kcol_s, kdst);
      int d = wid * 16 + vd_l;
      int scol = kt * 64 + (vslot << 4); if (scol > 2048) scol = 2048;
      load_lds16(vbb + (int64_t)d * 2064 + scol, vdst);
    }
    __syncthreads();

    // ---- fragments from LDS ----
    s8v kf[2][2];
    #pragma unroll
    for (int kc = 0; kc < 2; kc++){
      int roff = (kc * 16 + l15) << 7;
      #pragma unroll
      for (int ch = 0; ch < 2; ch++)
        kf[kc][ch] = *(const s8v*)((const char*)Kl + roff + ((((ch << 2) + g) ^ (l15 & 7)) << 4));
    }
    s4v vf[4][2];
    #pragma unroll
    for (int dc = 0; dc < 4; dc++){
      int doff = ((dc * 16 + l15) << 6) + ((g & 1) << 3);
      #pragma unroll
      for (int kc = 0; kc < 2; kc++)
        vf[dc][kc] = *(const s4v*)((const char*)Vl + doff + ((((kc << 1) + (g >> 1)) ^ vsw) << 4));
    }
    // rel_h rows
    int khA = kt - 1; if (khA < 0) khA = 0;
    int khB = kt; if (khB > 31) khB = 31;
    float rhA[2], rhB[2];
    #pragma unroll
    for (int qc = 0; qc < 2; qc++){
      rhA[qc] = rhbase[(int64_t)khA * 1024 + qp_[qc]];
      rhB[qc] = rhbase[(int64_t)khB * 1024 + qp_[qc]];
    }

    // ---- QK^T (swapped: lane col = query) ----
    f4v sv[2][2];
    #pragma unroll
    for (int qc = 0; qc < 2; qc++)
      #pragma unroll
      for (int kc = 0; kc < 2; kc++){
        f4v s = {0.f, 0.f, 0.f, 0.f};
        s = mfma32(kf[kc][0], qf[qc][0], s);
        s = mfma32(kf[kc][1], qf[qc][1], s);
        sv[qc][kc] = s;
      }

    const bool anyprompt = (kt == 0);
    const bool anymask = (kt == 32);
    s4v bp[2][2];
    #pragma unroll
    for (int qc = 0; qc < 2; qc++){
      const bool qpr = qn_[qc] < 8;
      float p[8];
      #pragma unroll
      for (int kc = 0; kc < 2; kc++)
        #pragma unroll
        for (int r = 0; r < 4; r++){
          int off = kc * 16 + g * 4 + r;
          float bias = qpr ? 0.f : ((off >= 8 ? rhB[qc] : rhA[qc]) + rw[qc][kc][r]);
          if (anyprompt && off < 8 && !qpr) bias = NEG;
          float L = fmaf(sv[qc][kc][r], C1, bias);
          if (anymask && off >= 8) L = NEG;
          p[kc * 4 + r] = exp2g(L);
        }
      lrun[qc] += ((p[0]+p[1])+(p[2]+p[3])) + ((p[4]+p[5])+(p[6]+p[7]));
      bp[qc][0] = pack4(p[0], p[1], p[2], p[3]);
      bp[qc][1] = pack4(p[4], p[5], p[6], p[7]);
    }
    // ---- PV ----
    #pragma unroll
    for (int dc = 0; dc < 4; dc++)
      #pragma unroll
      for (int kc = 0; kc < 2; kc++)
        #pragma unroll
        for (int qc = 0; qc < 2; qc++)
          of[dc][qc] = mfma16(vf[dc][kc], bp[qc][kc], of[dc][qc]);

    __syncthreads();   // all waves done reading before next stage overwrites
  }

  // ---- epilogue: l-reduce across g-groups, normalize, store ----
  #pragma unroll
  for (int qc = 0; qc < 2; qc++){
    int qn = qn_[qc];
    if (qn >= 1032) continue;
    float lt = lrun[qc];
    lt += __shfl_xor(lt, 16);
    lt += __shfl_xor(lt, 32);
    float inv = 1.0f / lt;
    unsigned short* dst = ao + ((int64_t)(b * 1032 + qn)) * 768 + head * 64;
    #pragma unroll
    for (int dc = 0; dc < 4; dc++){
      us4v pk = { f2bf(of[dc][qc][0] * inv), f2bf(of[dc][qc][1] * inv),
                  f2bf(of[dc][qc][2] * inv), f2bf(of[dc][qc][3] * inv) };
      *(us4v*)(dst + dc * 16 + g * 4) = pk;
    }
  }
}

extern "C" void kernel_launch(void* const* d_in, const int* in_sizes, int n_in,
                              void* d_out, int out_size, void* d_ws, size_t ws_size,
                              hipStream_t stream)
{
  const float* x   = (const float*)d_in[0];
  const float* vp  = (const float*)d_in[1];
  const float* qw  = (const float*)d_in[2];
  const float* qbb = (const float*)d_in[3];
  const float* pw  = (const float*)d_in[4];
  const float* pb  = (const float*)d_in[5];
  const float* rph = (const float*)d_in[6];
  const float* rpw = (const float*)d_in[7];
  float* out = (float*)d_out;

  char* ws = (char*)d_ws;
  size_t off = 0;
  auto alloc = [&](size_t bytes) -> void* {
    void* p = ws + off;
    off = (off + bytes + 255) & ~(size_t)255;
    return p;
  };
  unsigned short* xs   = (unsigned short*)alloc((size_t)8256 * 768 * 2);
  unsigned short* Wt   = (unsigned short*)alloc((size_t)2304 * 768 * 2);
  unsigned short* Pt   = (unsigned short*)alloc((size_t)768 * 768 * 2);
  unsigned short* qbuf = (unsigned short*)alloc((size_t)96 * 1032 * 64 * 2);
  unsigned short* kbuf = (unsigned short*)alloc((size_t)96 * 1032 * 64 * 2 + 4096);
  unsigned short* vtb  = (unsigned short*)alloc((size_t)96 * 64 * 1032 * 2 + 4096);
  float* relh = (float*)alloc((size_t)96 * 32 * 1024 * 4);
  float* relw = (float*)alloc((size_t)96 * 1024 * 32 * 4);
  unsigned short* ao = xs;  // xs dead after QKV GEMM; reuse for attention output

  k_prep<<<8496, 256, 0, stream>>>(x, vp, qw, pw, xs, Wt, Pt);
  k_gemm<0><<<dim3(18, 65), 256, 0, stream>>>(xs, Wt, qbb, 8256, 2304, 768,
                                              qbuf, kbuf, vtb, nullptr);
  k_rel<<<6144, 64, 0, stream>>>(qbuf, rph, rpw, relh, relw);
  k_attn<<<864, 256, 0, stream>>>(qbuf, kbuf, vtb, relh, relw, ao);
  k_gemm<1><<<dim3(6, 65), 256, 0, stream>>>(ao, Pt, pb, 8256, 768, 768,
                                             nullptr, nullptr, nullptr, out);
}

// Round 15
// 156.575 us; speedup vs baseline: 1.1274x; 1.0528x over previous
//
#include <hip/hip_runtime.h>
#include <stdint.h>

typedef __attribute__((ext_vector_type(8))) short s8v;
typedef __attribute__((ext_vector_type(4))) short s4v;
typedef __attribute__((ext_vector_type(4))) float f4v;
typedef __attribute__((ext_vector_type(4))) unsigned short us4v;
typedef __attribute__((ext_vector_type(4))) float f32x4v;

#define DEV static __device__ __forceinline__

#define L2E 1.44269504f

DEV unsigned short f2bf(float f){
  uint32_t x = __builtin_bit_cast(uint32_t, f);
  uint32_t r = x + 0x7fffu + ((x >> 16) & 1u);
  return (unsigned short)(r >> 16);
}

DEV float exp2g(float x){
#if __has_builtin(__builtin_amdgcn_exp2f)
  return __builtin_amdgcn_exp2f(x);
#else
  return exp2f(x);
#endif
}

// pack 4 f32 -> 4 bf16 (two v_cvt_pk_bf16_f32, RNE — same as f2bf)
DEV s4v pack4(float a, float b, float c, float d){
  uint32_t r0, r1;
  asm("v_cvt_pk_bf16_f32 %0, %1, %2" : "=v"(r0) : "v"(a), "v"(b));
  asm("v_cvt_pk_bf16_f32 %0, %1, %2" : "=v"(r1) : "v"(c), "v"(d));
  union { uint32_t u[2]; s4v s; } u; u.u[0] = r0; u.u[1] = r1; return u.s;
}

DEV f4v mfma32(s8v a, s8v b, f4v c){
  return __builtin_amdgcn_mfma_f32_16x16x32_bf16(a, b, c, 0, 0, 0);
}
DEV f4v mfma16(s4v a, s4v b, f4v c){
  return __builtin_amdgcn_mfma_f32_16x16x16bf16_1k(a, b, c, 0, 0, 0);
}

DEV void load_lds16(const void* g, void* l){
  __builtin_amdgcn_global_load_lds((const __attribute__((address_space(1))) uint32_t*)g,
                                   (__attribute__((address_space(3))) uint32_t*)l, 16, 0, 0);
}

// ---------------- fused prep: xs concat + W transposes ----------------
__global__ __launch_bounds__(256) void k_prep(const float* __restrict__ x,
    const float* __restrict__ vp, const float* __restrict__ qw,
    const float* __restrict__ pw, unsigned short* __restrict__ xs,
    unsigned short* __restrict__ Wt, unsigned short* __restrict__ Pt){
  __shared__ float tile[32][33];
  const int bid = blockIdx.x;
  if (bid < 6192){
    int64_t e = ((int64_t)bid * 256 + threadIdx.x) * 4;
    int m = (int)(e / 768); int c = (int)(e % 768);
    int b = m / 1032, n = m % 1032;
    const float* src = (n < 8) ? (vp + ((int64_t)(b * 8 + n)) * 768 + c)
                               : (x  + ((int64_t)(b * 1024 + (n - 8))) * 768 + c);
    f32x4v v = *(const f32x4v*)src;
    us4v o = { f2bf(v[0]), f2bf(v[1]), f2bf(v[2]), f2bf(v[3]) };
    *(us4v*)(xs + e) = o;
    return;
  }
  const int wb = bid - 6192;
  const float* src; unsigned short* dst; int Cc, j0, k0;
  if (wb < 1728){
    int jt = wb % 72, kt = wb / 72;
    src = qw; dst = Wt; Cc = 2304; k0 = kt * 32; j0 = jt * 32;
  } else {
    int t2 = wb - 1728;
    int jt = t2 % 24, kt = t2 / 24;
    src = pw; dst = Pt; Cc = 768; k0 = kt * 32; j0 = jt * 32;
  }
  const int t = threadIdx.x;
  const int r = t >> 3, c4 = (t & 7) * 4;
  f32x4v v = *(const f32x4v*)(src + (int64_t)(k0 + r) * Cc + j0 + c4);
  tile[r][c4 + 0] = v[0]; tile[r][c4 + 1] = v[1];
  tile[r][c4 + 2] = v[2]; tile[r][c4 + 3] = v[3];
  __syncthreads();
  us4v o = { f2bf(tile[c4 + 0][r]), f2bf(tile[c4 + 1][r]),
             f2bf(tile[c4 + 2][r]), f2bf(tile[c4 + 3][r]) };
  *(us4v*)(dst + (int64_t)(j0 + r) * 768 + k0 + c4) = o;
}

// ---------------- GEMM: C = A[M,K] * Bt[N,K]^T + bias, BK=64 ----------------
// Same macro-structure as all 14 passing rounds (stage -> barrier -> compute ->
// barrier; all loads pre-barrier, consumed within the interval) but two K-steps
// per interval: 8 global_load_lds per wave, then 2x(8 ds_read + 16 MFMA).
// LDS rows are 128B with 8-slot XOR swizzle (slot ^= row&7) -> <=2-way conflict.
// XCD-bijective block swizzle (m204) — verified in rounds 12/14.
template<int MODE>
__global__ __launch_bounds__(256) void k_gemm(
    const unsigned short* __restrict__ A, const unsigned short* __restrict__ Bt,
    const float* __restrict__ bias, int M, int N, int K,
    unsigned short* __restrict__ qb, unsigned short* __restrict__ kb,
    unsigned short* __restrict__ vtb, float* __restrict__ outp)
{
  __shared__ __align__(16) unsigned short At [128 * 64];   // 16KB
  __shared__ __align__(16) unsigned short Btl[128 * 64];   // 16KB
  const int tid = threadIdx.x, lane = tid & 63, wid = tid >> 6;
  const int nbx = gridDim.x, nwg = nbx * gridDim.y;
  const int bid = blockIdx.y * nbx + blockIdx.x;
  const int xcd = bid & 7, idx = bid >> 3;
  const int q8 = nwg >> 3, r8 = nwg & 7;
  const int wgid = (xcd < r8 ? xcd * (q8 + 1) : r8 * (q8 + 1) + (xcd - r8) * q8) + idx;
  const int mbase = (wgid / nbx) * 128, nbase = (wgid % nbx) * 128;
  const int wr = wid >> 1, wc = wid & 1;
  const int g = lane >> 4, l15 = lane & 15;
  f4v acc[4][4] = {};

  // staging: chunk c = wid*4+j covers rows c*8..c*8+7 (128B each).
  // lane covers row c*8+(lane>>3), slot (lane&7); source pre-swizzled so
  // LDS[row][slot] = G[row][slot ^ (row&7)].
  const int srl = lane >> 3;                 // row within chunk (== row&7)
  const int ssl = (lane & 7) ^ srl;          // pre-swizzled source slot
  const unsigned short* ap[4];
  const unsigned short* bp_[4];
  #pragma unroll
  for (int j = 0; j < 4; j++){
    int c = wid * 4 + j;
    int ar = mbase + c * 8 + srl; if (ar >= M) ar = 0;
    ap[j]  = A  + (int64_t)ar * K + ssl * 8;
    bp_[j] = Bt + (int64_t)(nbase + c * 8 + srl) * K + ssl * 8;
  }

  for (int ks = 0; ks < K; ks += 64){
    #pragma unroll
    for (int j = 0; j < 4; j++){
      load_lds16(ap[j]  + ks, (char*)At  + (wid * 4 + j) * 1024);
      load_lds16(bp_[j] + ks, (char*)Btl + (wid * 4 + j) * 1024);
    }
    __syncthreads();
    #pragma unroll
    for (int kk = 0; kk < 2; kk++){
      s8v af[4], bf[4];
      #pragma unroll
      for (int mc = 0; mc < 4; mc++){
        int row = wr * 64 + mc * 16 + l15;
        int o = row * 128 + (((kk * 4 + g) ^ (l15 & 7)) << 4);
        af[mc] = *(const s8v*)((const char*)At + o);
      }
      #pragma unroll
      for (int nc = 0; nc < 4; nc++){
        int row = wc * 64 + nc * 16 + l15;
        int o = row * 128 + (((kk * 4 + g) ^ (l15 & 7)) << 4);
        bf[nc] = *(const s8v*)((const char*)Btl + o);
      }
      #pragma unroll
      for (int mc = 0; mc < 4; mc++)
        #pragma unroll
        for (int nc = 0; nc < 4; nc++)
          acc[mc][nc] = mfma32(af[mc], bf[nc], acc[mc][nc]);
    }
    __syncthreads();
  }

  if (MODE == 0){
    const int which = nbase / 768;
    const int head  = ((nbase % 768) >> 6) + wc;
    #pragma unroll
    for (int nc = 0; nc < 4; nc++){
      int j = nbase + wc * 64 + nc * 16 + l15;
      float bv = bias[j];
      int d = nc * 16 + l15;
      #pragma unroll
      for (int mc = 0; mc < 4; mc++){
        int m0 = mbase + wr * 64 + mc * 16 + g * 4;
        if (m0 >= M) continue;
        int b = m0 / 1032, n = m0 % 1032;
        int bh = b * 12 + head;
        if (which == 2){
          us4v pk = { f2bf(acc[mc][nc][0] + bv), f2bf(acc[mc][nc][1] + bv),
                      f2bf(acc[mc][nc][2] + bv), f2bf(acc[mc][nc][3] + bv) };
          *(us4v*)(vtb + ((int64_t)bh * 64 + d) * 1032 + n) = pk;
        } else {
          unsigned short* dst = (which == 0 ? qb : kb) + ((int64_t)bh * 1032 + n) * 64 + d;
          #pragma unroll
          for (int r = 0; r < 4; r++) dst[(int64_t)r * 64] = f2bf(acc[mc][nc][r] + bv);
        }
      }
    }
  } else {
    #pragma unroll
    for (int nc = 0; nc < 4; nc++){
      int j = nbase + wc * 64 + nc * 16 + l15;
      float bv = bias[j];
      #pragma unroll
      for (int mc = 0; mc < 4; mc++){
        int m0 = mbase + wr * 64 + mc * 16 + g * 4;
        if (m0 >= M) continue;
        int b = m0 / 1032, n0 = m0 % 1032;
        #pragma unroll
        for (int r = 0; r < 4; r++){
          int n = n0 + r;
          float v = acc[mc][nc][r] + bv;
          int64_t dst = (n < 8) ? (6291456LL + ((int64_t)(b * 8 + n)) * 768 + j)
                                : (((int64_t)(b * 1024 + (n - 8))) * 768 + j);
          outp[dst] = v;
        }
      }
    }
  }
}

// ---------------- fused rel_h + rel_w (math verbatim r7) ----------------
__global__ __launch_bounds__(64) void k_rel(const unsigned short* __restrict__ qbuf,
    const float* __restrict__ rph, const float* __restrict__ rpw,
    float* __restrict__ relh, float* __restrict__ relw)
{
  const int lane = threadIdx.x;
  const int g = lane >> 4, l15 = lane & 15;
  if (blockIdx.x < 3072){
    const int bh = blockIdx.x >> 5;
    const int qh = blockIdx.x & 31;
    s8v qf[2][2];
    #pragma unroll
    for (int qc = 0; qc < 2; qc++){
      int n = qh * 32 + qc * 16 + l15 + 8;
      #pragma unroll
      for (int ch = 0; ch < 2; ch++)
        qf[qc][ch] = *(const s8v*)(qbuf + ((int64_t)bh * 1032 + n) * 64 + ch * 32 + g * 8);
    }
    s8v rf[2][2];
    #pragma unroll
    for (int kc = 0; kc < 2; kc++){
      int kh = kc * 16 + l15;
      #pragma unroll
      for (int ch = 0; ch < 2; ch++){
        const float* rp = rph + (int64_t)(qh - kh + 31) * 64 + ch * 32 + g * 8;
        f32x4v v0 = *(const f32x4v*)rp;
        f32x4v v1 = *(const f32x4v*)(rp + 4);
        s8v t = { (short)f2bf(v0[0]), (short)f2bf(v0[1]), (short)f2bf(v0[2]), (short)f2bf(v0[3]),
                  (short)f2bf(v1[0]), (short)f2bf(v1[1]), (short)f2bf(v1[2]), (short)f2bf(v1[3]) };
        rf[kc][ch] = t;
      }
    }
    #pragma unroll
    for (int kc = 0; kc < 2; kc++)
      #pragma unroll
      for (int qc = 0; qc < 2; qc++){
        f4v d = {0.f, 0.f, 0.f, 0.f};
        d = mfma32(rf[kc][0], qf[qc][0], d);
        d = mfma32(rf[kc][1], qf[qc][1], d);
        #pragma unroll
        for (int r = 0; r < 4; r++)
          relh[((int64_t)bh * 32 + kc * 16 + g * 4 + r) * 1024 + qh * 32 + qc * 16 + l15] = d[r] * L2E;
      }
  } else {
    const int bid = blockIdx.x - 3072;
    const int bh = bid >> 5;
    const int qw = bid & 31;
    s8v qf[2][2];
    #pragma unroll
    for (int qc = 0; qc < 2; qc++){
      int qp = qw + 32 * (qc * 16 + l15);
      int n = qp + 8;
      #pragma unroll
      for (int ch = 0; ch < 2; ch++)
        qf[qc][ch] = *(const s8v*)(qbuf + ((int64_t)bh * 1032 + n) * 64 + ch * 32 + g * 8);
    }
    s8v wf[2][2];
    #pragma unroll
    for (int kc = 0; kc < 2; kc++){
      int kw = kc * 16 + l15;
      #pragma unroll
      for (int ch = 0; ch < 2; ch++){
        const float* rp = rpw + (int64_t)(qw - kw + 31) * 64 + ch * 32 + g * 8;
        f32x4v v0 = *(const f32x4v*)rp;
        f32x4v v1 = *(const f32x4v*)(rp + 4);
        s8v t = { (short)f2bf(v0[0]), (short)f2bf(v0[1]), (short)f2bf(v0[2]), (short)f2bf(v0[3]),
                  (short)f2bf(v1[0]), (short)f2bf(v1[1]), (short)f2bf(v1[2]), (short)f2bf(v1[3]) };
        wf[kc][ch] = t;
      }
    }
    #pragma unroll
    for (int qc = 0; qc < 2; qc++)
      #pragma unroll
      for (int kc = 0; kc < 2; kc++){
        f4v d = {0.f, 0.f, 0.f, 0.f};
        d = mfma32(qf[qc][0], wf[kc][0], d);
        d = mfma32(qf[qc][1], wf[kc][1], d);
        #pragma unroll
        for (int r = 0; r < 4; r++){
          int qp = qw + 32 * (qc * 16 + g * 4 + r);
          relw[((int64_t)bh * 1024 + qp) * 32 + kc * 16 + l15] = d[r] * L2E;
        }
      }
  }
}

// ---------------- flash attention, LDS-staged K/V shared by 4 waves ----------------
// VERBATIM round-11/14 version (passed 3x: r7, r11, r14 @70.3-70.5us). FROZEN.
__global__ __launch_bounds__(256, 3) void k_attn(
    const unsigned short* __restrict__ qb, const unsigned short* __restrict__ kb,
    const unsigned short* __restrict__ vtb, const float* __restrict__ relh,
    const float* __restrict__ relw, unsigned short* __restrict__ ao)
{
  const int lane = threadIdx.x & 63, wid = threadIdx.x >> 6;
  // XCD-bijective swizzle: 864 = 8 * 108
  const int wq = (blockIdx.x & 7) * 108 + (blockIdx.x >> 3);
  const int bh = wq / 9;
  const int qg = wq % 9;
  int qt = qg * 4 + wid; if (qt > 32) qt = 32;   // dup waves write identical data
  const int qbase = qt * 32;
  const int g = lane >> 4, l15 = lane & 15;
  const int b = bh / 12, head = bh % 12;
  const float C1 = 0.125f * L2E;
  const float NEG = -144.269504f;   // exp2 -> 0

  __shared__ __align__(16) unsigned short Kl[32 * 64];  // 4KB, row=128B, slot^=(r&7)
  __shared__ __align__(16) unsigned short Vl[64 * 32];  // 4KB, row=64B,  slot^=((d^(d>>2))&3)

  f4v of[4][2] = {};
  float lrun[2] = {0.f, 0.f};
  int qn_[2], qp_[2];

  s8v qf[2][2];
  float rw[2][2][4];
  #pragma unroll
  for (int qc = 0; qc < 2; qc++){
    int qn = qbase + qc * 16 + l15;
    qn_[qc] = qn;
    int qcl = qn < 1032 ? qn : 1031;
    #pragma unroll
    for (int ch = 0; ch < 2; ch++)
      qf[qc][ch] = *(const s8v*)(qb + ((int64_t)bh * 1032 + qcl) * 64 + ch * 32 + g * 8);
    int qp = qn - 8; if (qp < 0) qp = 0; if (qp > 1023) qp = 1023;
    qp_[qc] = qp;
  }
  #pragma unroll
  for (int qc = 0; qc < 2; qc++)
    #pragma unroll
    for (int kc = 0; kc < 2; kc++)
      #pragma unroll
      for (int r = 0; r < 4; r++){
        int kw = (kc * 16 + g * 4 + r + 24) & 31;
        rw[qc][kc][r] = relw[((int64_t)bh * 1024 + qp_[qc]) * 32 + kw];
      }

  const char* kbb = (const char*)(kb + (int64_t)bh * 1032 * 64);
  const char* vbb = (const char*)(vtb + (int64_t)bh * 64 * 1032);
  const float* rhbase = relh + (int64_t)bh * 32 * 1024;

  // staging geometry (per wave; lane's LDS dest = base + lane*16, HW-linear)
  const int krow_l = (lane >> 3);                    // 0..7 within wave's 8 rows
  const int kcol_s = ((lane & 7) ^ krow_l) << 4;     // pre-swizzled col byte
  const int vd_l   = (lane >> 2);                    // 0..15 within wave's 16 rows
  const int vslot  = ((lane & 3) ^ ((lane >> 2) ^ (lane >> 4)) & 3);
  char* kdst = (char*)Kl + wid * 1024;
  char* vdst = (char*)Vl + wid * 1024;
  const int vsw = (l15 ^ (l15 >> 2)) & 3;            // read-side V swizzle

  for (int kt = 0; kt < 33; kt++){
    // ---- stage tile kt (4 waves cooperatively; clamped sources stay finite) ----
    {
      int gr = kt * 32 + wid * 8 + krow_l; if (gr > 1031) gr = 1031;
      load_lds16(kbb + (int64_t)gr * 128 + kcol_s, kdst);
      int d = wid * 16 + vd_l;
      int scol = kt * 64 + (vslot << 4); if (scol > 2048) scol = 2048;
      load_lds16(vbb + (int64_t)d * 2064 + scol, vdst);
    }
    __syncthreads();

    // ---- fragments from LDS ----
    s8v kf[2][2];
    #pragma unroll
    for (int kc = 0; kc < 2; kc++){
      int roff = (kc * 16 + l15) << 7;
      #pragma unroll
      for (int ch = 0; ch < 2; ch++)
        kf[kc][ch] = *(const s8v*)((const char*)Kl + roff + ((((ch << 2) + g) ^ (l15 & 7)) << 4));
    }
    s4v vf[4][2];
    #pragma unroll
    for (int dc = 0; dc < 4; dc++){
      int doff = ((dc * 16 + l15) << 6) + ((g & 1) << 3);
      #pragma unroll
      for (int kc = 0; kc < 2; kc++)
        vf[dc][kc] = *(const s4v*)((const char*)Vl + doff + ((((kc << 1) + (g >> 1)) ^ vsw) << 4));
    }
    // rel_h rows
    int khA = kt - 1; if (khA < 0) khA = 0;
    int khB = kt; if (khB > 31) khB = 31;
    float rhA[2], rhB[2];
    #pragma unroll
    for (int qc = 0; qc < 2; qc++){
      rhA[qc] = rhbase[(int64_t)khA * 1024 + qp_[qc]];
      rhB[qc] = rhbase[(int64_t)khB * 1024 + qp_[qc]];
    }

    // ---- QK^T (swapped: lane col = query) ----
    f4v sv[2][2];
    #pragma unroll
    for (int qc = 0; qc < 2; qc++)
      #pragma unroll
      for (int kc = 0; kc < 2; kc++){
        f4v s = {0.f, 0.f, 0.f, 0.f};
        s = mfma32(kf[kc][0], qf[qc][0], s);
        s = mfma32(kf[kc][1], qf[qc][1], s);
        sv[qc][kc] = s;
      }

    const bool anyprompt = (kt == 0);
    const bool anymask = (kt == 32);
    s4v bp[2][2];
    #pragma unroll
    for (int qc = 0; qc < 2; qc++){
      const bool qpr = qn_[qc] < 8;
      float p[8];
      #pragma unroll
      for (int kc = 0; kc < 2; kc++)
        #pragma unroll
        for (int r = 0; r < 4; r++){
          int off = kc * 16 + g * 4 + r;
          float bias = qpr ? 0.f : ((off >= 8 ? rhB[qc] : rhA[qc]) + rw[qc][kc][r]);
          if (anyprompt && off < 8 && !qpr) bias = NEG;
          float L = fmaf(sv[qc][kc][r], C1, bias);
          if (anymask && off >= 8) L = NEG;
          p[kc * 4 + r] = exp2g(L);
        }
      lrun[qc] += ((p[0]+p[1])+(p[2]+p[3])) + ((p[4]+p[5])+(p[6]+p[7]));
      bp[qc][0] = pack4(p[0], p[1], p[2], p[3]);
      bp[qc][1] = pack4(p[4], p[5], p[6], p[7]);
    }
    // ---- PV ----
    #pragma unroll
    for (int dc = 0; dc < 4; dc++)
      #pragma unroll
      for (int kc = 0; kc < 2; kc++)
        #pragma unroll
        for (int qc = 0; qc < 2; qc++)
          of[dc][qc] = mfma16(vf[dc][kc], bp[qc][kc], of[dc][qc]);

    __syncthreads();   // all waves done reading before next stage overwrites
  }

  // ---- epilogue: l-reduce across g-groups, normalize, store ----
  #pragma unroll
  for (int qc = 0; qc < 2; qc++){
    int qn = qn_[qc];
    if (qn >= 1032) continue;
    float lt = lrun[qc];
    lt += __shfl_xor(lt, 16);
    lt += __shfl_xor(lt, 32);
    float inv = 1.0f / lt;
    unsigned short* dst = ao + ((int64_t)(b * 1032 + qn)) * 768 + head * 64;
    #pragma unroll
    for (int dc = 0; dc < 4; dc++){
      us4v pk = { f2bf(of[dc][qc][0] * inv), f2bf(of[dc][qc][1] * inv),
                  f2bf(of[dc][qc][2] * inv), f2bf(of[dc][qc][3] * inv) };
      *(us4v*)(dst + dc * 16 + g * 4) = pk;
    }
  }
}

extern "C" void kernel_launch(void* const* d_in, const int* in_sizes, int n_in,
                              void* d_out, int out_size, void* d_ws, size_t ws_size,
                              hipStream_t stream)
{
  const float* x   = (const float*)d_in[0];
  const float* vp  = (const float*)d_in[1];
  const float* qw  = (const float*)d_in[2];
  const float* qbb = (const float*)d_in[3];
  const float* pw  = (const float*)d_in[4];
  const float* pb  = (const float*)d_in[5];
  const float* rph = (const float*)d_in[6];
  const float* rpw = (const float*)d_in[7];
  float* out = (float*)d_out;

  char* ws = (char*)d_ws;
  size_t off = 0;
  auto alloc = [&](size_t bytes) -> void* {
    void* p = ws + off;
    off = (off + bytes + 255) & ~(size_t)255;
    return p;
  };
  unsigned short* xs   = (unsigned short*)alloc((size_t)8256 * 768 * 2);
  unsigned short* Wt   = (unsigned short*)alloc((size_t)2304 * 768 * 2);
  unsigned short* Pt   = (unsigned short*)alloc((size_t)768 * 768 * 2);
  unsigned short* qbuf = (unsigned short*)alloc((size_t)96 * 1032 * 64 * 2);
  unsigned short* kbuf = (unsigned short*)alloc((size_t)96 * 1032 * 64 * 2 + 4096);
  unsigned short* vtb  = (unsigned short*)alloc((size_t)96 * 64 * 1032 * 2 + 4096);
  float* relh = (float*)alloc((size_t)96 * 32 * 1024 * 4);
  float* relw = (float*)alloc((size_t)96 * 1024 * 32 * 4);
  unsigned short* ao = xs;  // xs dead after QKV GEMM; reuse for attention output

  k_prep<<<8496, 256, 0, stream>>>(x, vp, qw, pw, xs, Wt, Pt);
  k_gemm<0><<<dim3(18, 65), 256, 0, stream>>>(xs, Wt, qbb, 8256, 2304, 768,
                                              qbuf, kbuf, vtb, nullptr);
  k_rel<<<6144, 64, 0, stream>>>(qbuf, rph, rpw, relh, relw);
  k_attn<<<864, 256, 0, stream>>>(qbuf, kbuf, vtb, relh, relw, ao);
  k_gemm<1><<<dim3(6, 65), 256, 0, stream>>>(ao, Pt, pb, 8256, 768, 768,
                                             nullptr, nullptr, nullptr, out);
}

// Round 16
// 153.517 us; speedup vs baseline: 1.1499x; 1.0199x over previous
//
#include <hip/hip_runtime.h>
#include <stdint.h>

typedef __attribute__((ext_vector_type(8))) short s8v;
typedef __attribute__((ext_vector_type(4))) short s4v;
typedef __attribute__((ext_vector_type(4))) float f4v;
typedef __attribute__((ext_vector_type(4))) unsigned short us4v;
typedef __attribute__((ext_vector_type(4))) float f32x4v;

#define DEV static __device__ __forceinline__

#define L2E 1.44269504f

DEV unsigned short f2bf(float f){
  uint32_t x = __builtin_bit_cast(uint32_t, f);
  uint32_t r = x + 0x7fffu + ((x >> 16) & 1u);
  return (unsigned short)(r >> 16);
}

DEV float exp2g(float x){
#if __has_builtin(__builtin_amdgcn_exp2f)
  return __builtin_amdgcn_exp2f(x);
#else
  return exp2f(x);
#endif
}

// pack 4 f32 -> 4 bf16 (two v_cvt_pk_bf16_f32, RNE — same as f2bf)
DEV s4v pack4(float a, float b, float c, float d){
  uint32_t r0, r1;
  asm("v_cvt_pk_bf16_f32 %0, %1, %2" : "=v"(r0) : "v"(a), "v"(b));
  asm("v_cvt_pk_bf16_f32 %0, %1, %2" : "=v"(r1) : "v"(c), "v"(d));
  union { uint32_t u[2]; s4v s; } u; u.u[0] = r0; u.u[1] = r1; return u.s;
}

DEV f4v mfma32(s8v a, s8v b, f4v c){
  return __builtin_amdgcn_mfma_f32_16x16x32_bf16(a, b, c, 0, 0, 0);
}
DEV f4v mfma16(s4v a, s4v b, f4v c){
  return __builtin_amdgcn_mfma_f32_16x16x16bf16_1k(a, b, c, 0, 0, 0);
}

DEV void load_lds16(const void* g, void* l){
  __builtin_amdgcn_global_load_lds((const __attribute__((address_space(1))) uint32_t*)g,
                                   (__attribute__((address_space(3))) uint32_t*)l, 16, 0, 0);
}

// ---------------- fused prep: xs concat + W transposes ----------------
__global__ __launch_bounds__(256) void k_prep(const float* __restrict__ x,
    const float* __restrict__ vp, const float* __restrict__ qw,
    const float* __restrict__ pw, unsigned short* __restrict__ xs,
    unsigned short* __restrict__ Wt, unsigned short* __restrict__ Pt){
  __shared__ float tile[32][33];
  const int bid = blockIdx.x;
  if (bid < 6192){
    int64_t e = ((int64_t)bid * 256 + threadIdx.x) * 4;
    int m = (int)(e / 768); int c = (int)(e % 768);
    int b = m / 1032, n = m % 1032;
    const float* src = (n < 8) ? (vp + ((int64_t)(b * 8 + n)) * 768 + c)
                               : (x  + ((int64_t)(b * 1024 + (n - 8))) * 768 + c);
    f32x4v v = *(const f32x4v*)src;
    us4v o = { f2bf(v[0]), f2bf(v[1]), f2bf(v[2]), f2bf(v[3]) };
    *(us4v*)(xs + e) = o;
    return;
  }
  const int wb = bid - 6192;
  const float* src; unsigned short* dst; int Cc, j0, k0;
  if (wb < 1728){
    int jt = wb % 72, kt = wb / 72;
    src = qw; dst = Wt; Cc = 2304; k0 = kt * 32; j0 = jt * 32;
  } else {
    int t2 = wb - 1728;
    int jt = t2 % 24, kt = t2 / 24;
    src = pw; dst = Pt; Cc = 768; k0 = kt * 32; j0 = jt * 32;
  }
  const int t = threadIdx.x;
  const int r = t >> 3, c4 = (t & 7) * 4;
  f32x4v v = *(const f32x4v*)(src + (int64_t)(k0 + r) * Cc + j0 + c4);
  tile[r][c4 + 0] = v[0]; tile[r][c4 + 1] = v[1];
  tile[r][c4 + 2] = v[2]; tile[r][c4 + 3] = v[3];
  __syncthreads();
  us4v o = { f2bf(tile[c4 + 0][r]), f2bf(tile[c4 + 1][r]),
             f2bf(tile[c4 + 2][r]), f2bf(tile[c4 + 3][r]) };
  *(us4v*)(dst + (int64_t)(j0 + r) * 768 + k0 + c4) = o;
}

// ---------------- GEMM: C = A[M,K] * Bt[N,K]^T + bias, BK=64, tile 128xTN ----------------
// r15's proven BK=64 structure, generalized over tile-N width (TN). MODE 0 uses
// TN=128 (epilogue indices unchanged from the 15/15-green version); MODE 1 uses
// TN=64 -> 780 blocks (3.05/CU) instead of 390 (1.52/CU convoy imbalance).
// XCD-bijective block swizzle (m204) — verified rounds 12/14/15.
template<int MODE, int TN>
__global__ __launch_bounds__(256) void k_gemm(
    const unsigned short* __restrict__ A, const unsigned short* __restrict__ Bt,
    const float* __restrict__ bias, int M, int N, int K,
    unsigned short* __restrict__ qb, unsigned short* __restrict__ kb,
    unsigned short* __restrict__ vtb, float* __restrict__ outp)
{
  constexpr int NC  = TN / 32;   // col fragments per wave
  constexpr int CPW = TN / 32;   // B-staging chunks per wave
  __shared__ __align__(16) unsigned short At [128 * 64];   // 16KB
  __shared__ __align__(16) unsigned short Btl[TN * 64];    // 16KB or 8KB
  const int tid = threadIdx.x, lane = tid & 63, wid = tid >> 6;
  const int nbx = gridDim.x, nwg = nbx * gridDim.y;
  const int bid = blockIdx.y * nbx + blockIdx.x;
  const int xcd = bid & 7, idx = bid >> 3;
  const int q8 = nwg >> 3, r8 = nwg & 7;
  const int wgid = (xcd < r8 ? xcd * (q8 + 1) : r8 * (q8 + 1) + (xcd - r8) * q8) + idx;
  const int mbase = (wgid / nbx) * 128, nbase = (wgid % nbx) * TN;
  const int wr = wid >> 1, wc = wid & 1;
  const int wcol = wc * (TN / 2);
  const int g = lane >> 4, l15 = lane & 15;
  f4v acc[4][NC] = {};

  // staging: chunk covers 8 rows of 128B; lane covers row c*8+(lane>>3),
  // slot (lane&7); source pre-swizzled so LDS[row][slot] = G[row][slot^(row&7)].
  const int srl = lane >> 3;
  const int ssl = (lane & 7) ^ srl;
  const unsigned short* ap[4];
  const unsigned short* bp_[CPW];
  #pragma unroll
  for (int j = 0; j < 4; j++){
    int c = wid * 4 + j;
    int ar = mbase + c * 8 + srl; if (ar >= M) ar = 0;
    ap[j] = A + (int64_t)ar * K + ssl * 8;
  }
  #pragma unroll
  for (int j = 0; j < CPW; j++){
    int c = wid * CPW + j;
    bp_[j] = Bt + (int64_t)(nbase + c * 8 + srl) * K + ssl * 8;
  }

  for (int ks = 0; ks < K; ks += 64){
    #pragma unroll
    for (int j = 0; j < 4; j++)
      load_lds16(ap[j] + ks, (char*)At + (wid * 4 + j) * 1024);
    #pragma unroll
    for (int j = 0; j < CPW; j++)
      load_lds16(bp_[j] + ks, (char*)Btl + (wid * CPW + j) * 1024);
    __syncthreads();
    #pragma unroll
    for (int kk = 0; kk < 2; kk++){
      s8v af[4], bf[NC];
      #pragma unroll
      for (int mc = 0; mc < 4; mc++){
        int row = wr * 64 + mc * 16 + l15;
        int o = row * 128 + (((kk * 4 + g) ^ (l15 & 7)) << 4);
        af[mc] = *(const s8v*)((const char*)At + o);
      }
      #pragma unroll
      for (int nc = 0; nc < NC; nc++){
        int row = wcol + nc * 16 + l15;
        int o = row * 128 + (((kk * 4 + g) ^ (l15 & 7)) << 4);
        bf[nc] = *(const s8v*)((const char*)Btl + o);
      }
      #pragma unroll
      for (int mc = 0; mc < 4; mc++)
        #pragma unroll
        for (int nc = 0; nc < NC; nc++)
          acc[mc][nc] = mfma32(af[mc], bf[nc], acc[mc][nc]);
    }
    __syncthreads();
  }

  if (MODE == 0){
    const int which = nbase / 768;
    const int head  = ((nbase % 768) >> 6) + wc;
    #pragma unroll
    for (int nc = 0; nc < NC; nc++){
      int j = nbase + wcol + nc * 16 + l15;
      float bv = bias[j];
      int d = nc * 16 + l15;
      #pragma unroll
      for (int mc = 0; mc < 4; mc++){
        int m0 = mbase + wr * 64 + mc * 16 + g * 4;
        if (m0 >= M) continue;
        int b = m0 / 1032, n = m0 % 1032;
        int bh = b * 12 + head;
        if (which == 2){
          us4v pk = { f2bf(acc[mc][nc][0] + bv), f2bf(acc[mc][nc][1] + bv),
                      f2bf(acc[mc][nc][2] + bv), f2bf(acc[mc][nc][3] + bv) };
          *(us4v*)(vtb + ((int64_t)bh * 64 + d) * 1032 + n) = pk;
        } else {
          unsigned short* dst = (which == 0 ? qb : kb) + ((int64_t)bh * 1032 + n) * 64 + d;
          #pragma unroll
          for (int r = 0; r < 4; r++) dst[(int64_t)r * 64] = f2bf(acc[mc][nc][r] + bv);
        }
      }
    }
  } else {
    #pragma unroll
    for (int nc = 0; nc < NC; nc++){
      int j = nbase + wcol + nc * 16 + l15;
      float bv = bias[j];
      #pragma unroll
      for (int mc = 0; mc < 4; mc++){
        int m0 = mbase + wr * 64 + mc * 16 + g * 4;
        if (m0 >= M) continue;
        int b = m0 / 1032, n0 = m0 % 1032;
        #pragma unroll
        for (int r = 0; r < 4; r++){
          int n = n0 + r;
          float v = acc[mc][nc][r] + bv;
          int64_t dst = (n < 8) ? (6291456LL + ((int64_t)(b * 8 + n)) * 768 + j)
                                : (((int64_t)(b * 1024 + (n - 8))) * 768 + j);
          outp[dst] = v;
        }
      }
    }
  }
}

// ---------------- fused rel_h + rel_w (math verbatim r7) ----------------
__global__ __launch_bounds__(64) void k_rel(const unsigned short* __restrict__ qbuf,
    const float* __restrict__ rph, const float* __restrict__ rpw,
    float* __restrict__ relh, float* __restrict__ relw)
{
  const int lane = threadIdx.x;
  const int g = lane >> 4, l15 = lane & 15;
  if (blockIdx.x < 3072){
    const int bh = blockIdx.x >> 5;
    const int qh = blockIdx.x & 31;
    s8v qf[2][2];
    #pragma unroll
    for (int qc = 0; qc < 2; qc++){
      int n = qh * 32 + qc * 16 + l15 + 8;
      #pragma unroll
      for (int ch = 0; ch < 2; ch++)
        qf[qc][ch] = *(const s8v*)(qbuf + ((int64_t)bh * 1032 + n) * 64 + ch * 32 + g * 8);
    }
    s8v rf[2][2];
    #pragma unroll
    for (int kc = 0; kc < 2; kc++){
      int kh = kc * 16 + l15;
      #pragma unroll
      for (int ch = 0; ch < 2; ch++){
        const float* rp = rph + (int64_t)(qh - kh + 31) * 64 + ch * 32 + g * 8;
        f32x4v v0 = *(const f32x4v*)rp;
        f32x4v v1 = *(const f32x4v*)(rp + 4);
        s8v t = { (short)f2bf(v0[0]), (short)f2bf(v0[1]), (short)f2bf(v0[2]), (short)f2bf(v0[3]),
                  (short)f2bf(v1[0]), (short)f2bf(v1[1]), (short)f2bf(v1[2]), (short)f2bf(v1[3]) };
        rf[kc][ch] = t;
      }
    }
    #pragma unroll
    for (int kc = 0; kc < 2; kc++)
      #pragma unroll
      for (int qc = 0; qc < 2; qc++){
        f4v d = {0.f, 0.f, 0.f, 0.f};
        d = mfma32(rf[kc][0], qf[qc][0], d);
        d = mfma32(rf[kc][1], qf[qc][1], d);
        #pragma unroll
        for (int r = 0; r < 4; r++)
          relh[((int64_t)bh * 32 + kc * 16 + g * 4 + r) * 1024 + qh * 32 + qc * 16 + l15] = d[r] * L2E;
      }
  } else {
    const int bid = blockIdx.x - 3072;
    const int bh = bid >> 5;
    const int qw = bid & 31;
    s8v qf[2][2];
    #pragma unroll
    for (int qc = 0; qc < 2; qc++){
      int qp = qw + 32 * (qc * 16 + l15);
      int n = qp + 8;
      #pragma unroll
      for (int ch = 0; ch < 2; ch++)
        qf[qc][ch] = *(const s8v*)(qbuf + ((int64_t)bh * 1032 + n) * 64 + ch * 32 + g * 8);
    }
    s8v wf[2][2];
    #pragma unroll
    for (int kc = 0; kc < 2; kc++){
      int kw = kc * 16 + l15;
      #pragma unroll
      for (int ch = 0; ch < 2; ch++){
        const float* rp = rpw + (int64_t)(qw - kw + 31) * 64 + ch * 32 + g * 8;
        f32x4v v0 = *(const f32x4v*)rp;
        f32x4v v1 = *(const f32x4v*)(rp + 4);
        s8v t = { (short)f2bf(v0[0]), (short)f2bf(v0[1]), (short)f2bf(v0[2]), (short)f2bf(v0[3]),
                  (short)f2bf(v1[0]), (short)f2bf(v1[1]), (short)f2bf(v1[2]), (short)f2bf(v1[3]) };
        wf[kc][ch] = t;
      }
    }
    #pragma unroll
    for (int qc = 0; qc < 2; qc++)
      #pragma unroll
      for (int kc = 0; kc < 2; kc++){
        f4v d = {0.f, 0.f, 0.f, 0.f};
        d = mfma32(qf[qc][0], wf[kc][0], d);
        d = mfma32(qf[qc][1], wf[kc][1], d);
        #pragma unroll
        for (int r = 0; r < 4; r++){
          int qp = qw + 32 * (qc * 16 + g * 4 + r);
          relw[((int64_t)bh * 1024 + qp) * 32 + kc * 16 + l15] = d[r] * L2E;
        }
      }
  }
}

// ---------------- flash attention, LDS-staged K/V shared by 4 waves ----------------
// VERBATIM round-11/14/15 version (passed 4x @70.2-70.7us). FROZEN.
__global__ __launch_bounds__(256, 3) void k_attn(
    const unsigned short* __restrict__ qb, const unsigned short* __restrict__ kb,
    const unsigned short* __restrict__ vtb, const float* __restrict__ relh,
    const float* __restrict__ relw, unsigned short* __restrict__ ao)
{
  const int lane = threadIdx.x & 63, wid = threadIdx.x >> 6;
  // XCD-bijective swizzle: 864 = 8 * 108
  const int wq = (blockIdx.x & 7) * 108 + (blockIdx.x >> 3);
  const int bh = wq / 9;
  const int qg = wq % 9;
  int qt = qg * 4 + wid; if (qt > 32) qt = 32;   // dup waves write identical data
  const int qbase = qt * 32;
  const int g = lane >> 4, l15 = lane & 15;
  const int b = bh / 12, head = bh % 12;
  const float C1 = 0.125f * L2E;
  const float NEG = -144.269504f;   // exp2 -> 0

  __shared__ __align__(16) unsigned short Kl[32 * 64];  // 4KB, row=128B, slot^=(r&7)
  __shared__ __align__(16) unsigned short Vl[64 * 32];  // 4KB, row=64B,  slot^=((d^(d>>2))&3)

  f4v of[4][2] = {};
  float lrun[2] = {0.f, 0.f};
  int qn_[2], qp_[2];

  s8v qf[2][2];
  float rw[2][2][4];
  #pragma unroll
  for (int qc = 0; qc < 2; qc++){
    int qn = qbase + qc * 16 + l15;
    qn_[qc] = qn;
    int qcl = qn < 1032 ? qn : 1031;
    #pragma unroll
    for (int ch = 0; ch < 2; ch++)
      qf[qc][ch] = *(const s8v*)(qb + ((int64_t)bh * 1032 + qcl) * 64 + ch * 32 + g * 8);
    int qp = qn - 8; if (qp < 0) qp = 0; if (qp > 1023) qp = 1023;
    qp_[qc] = qp;
  }
  #pragma unroll
  for (int qc = 0; qc < 2; qc++)
    #pragma unroll
    for (int kc = 0; kc < 2; kc++)
      #pragma unroll
      for (int r = 0; r < 4; r++){
        int kw = (kc * 16 + g * 4 + r + 24) & 31;
        rw[qc][kc][r] = relw[((int64_t)bh * 1024 + qp_[qc]) * 32 + kw];
      }

  const char* kbb = (const char*)(kb + (int64_t)bh * 1032 * 64);
  const char* vbb = (const char*)(vtb + (int64_t)bh * 64 * 1032);
  const float* rhbase = relh + (int64_t)bh * 32 * 1024;

  // staging geometry (per wave; lane's LDS dest = base + lane*16, HW-linear)
  const int krow_l = (lane >> 3);                    // 0..7 within wave's 8 rows
  const int kcol_s = ((lane & 7) ^ krow_l) << 4;     // pre-swizzled col byte
  const int vd_l   = (lane >> 2);                    // 0..15 within wave's 16 rows
  const int vslot  = ((lane & 3) ^ ((lane >> 2) ^ (lane >> 4)) & 3);
  char* kdst = (char*)Kl + wid * 1024;
  char* vdst = (char*)Vl + wid * 1024;
  const int vsw = (l15 ^ (l15 >> 2)) & 3;            // read-side V swizzle

  for (int kt = 0; kt < 33; kt++){
    // ---- stage tile kt (4 waves cooperatively; clamped sources stay finite) ----
    {
      int gr = kt * 32 + wid * 8 + krow_l; if (gr > 1031) gr = 1031;
      load_lds16(kbb + (int64_t)gr * 128 + kcol_s, kdst);
      int d = wid * 16 + vd_l;
      int scol = kt * 64 + (vslot << 4); if (scol > 2048) scol = 2048;
      load_lds16(vbb + (int64_t)d * 2064 + scol, vdst);
    }
    __syncthreads();

    // ---- fragments from LDS ----
    s8v kf[2][2];
    #pragma unroll
    for (int kc = 0; kc < 2; kc++){
      int roff = (kc * 16 + l15) << 7;
      #pragma unroll
      for (int ch = 0; ch < 2; ch++)
        kf[kc][ch] = *(const s8v*)((const char*)Kl + roff + ((((ch << 2) + g) ^ (l15 & 7)) << 4));
    }
    s4v vf[4][2];
    #pragma unroll
    for (int dc = 0; dc < 4; dc++){
      int doff = ((dc * 16 + l15) << 6) + ((g & 1) << 3);
      #pragma unroll
      for (int kc = 0; kc < 2; kc++)
        vf[dc][kc] = *(const s4v*)((const char*)Vl + doff + ((((kc << 1) + (g >> 1)) ^ vsw) << 4));
    }
    // rel_h rows
    int khA = kt - 1; if (khA < 0) khA = 0;
    int khB = kt; if (khB > 31) khB = 31;
    float rhA[2], rhB[2];
    #pragma unroll
    for (int qc = 0; qc < 2; qc++){
      rhA[qc] = rhbase[(int64_t)khA * 1024 + qp_[qc]];
      rhB[qc] = rhbase[(int64_t)khB * 1024 + qp_[qc]];
    }

    // ---- QK^T (swapped: lane col = query) ----
    f4v sv[2][2];
    #pragma unroll
    for (int qc = 0; qc < 2; qc++)
      #pragma unroll
      for (int kc = 0; kc < 2; kc++){
        f4v s = {0.f, 0.f, 0.f, 0.f};
        s = mfma32(kf[kc][0], qf[qc][0], s);
        s = mfma32(kf[kc][1], qf[qc][1], s);
        sv[qc][kc] = s;
      }

    const bool anyprompt = (kt == 0);
    const bool anymask = (kt == 32);
    s4v bp[2][2];
    #pragma unroll
    for (int qc = 0; qc < 2; qc++){
      const bool qpr = qn_[qc] < 8;
      float p[8];
      #pragma unroll
      for (int kc = 0; kc < 2; kc++)
        #pragma unroll
        for (int r = 0; r < 4; r++){
          int off = kc * 16 + g * 4 + r;
          float bias = qpr ? 0.f : ((off >= 8 ? rhB[qc] : rhA[qc]) + rw[qc][kc][r]);
          if (anyprompt && off < 8 && !qpr) bias = NEG;
          float L = fmaf(sv[qc][kc][r], C1, bias);
          if (anymask && off >= 8) L = NEG;
          p[kc * 4 + r] = exp2g(L);
        }
      lrun[qc] += ((p[0]+p[1])+(p[2]+p[3])) + ((p[4]+p[5])+(p[6]+p[7]));
      bp[qc][0] = pack4(p[0], p[1], p[2], p[3]);
      bp[qc][1] = pack4(p[4], p[5], p[6], p[7]);
    }
    // ---- PV ----
    #pragma unroll
    for (int dc = 0; dc < 4; dc++)
      #pragma unroll
      for (int kc = 0; kc < 2; kc++)
        #pragma unroll
        for (int qc = 0; qc < 2; qc++)
          of[dc][qc] = mfma16(vf[dc][kc], bp[qc][kc], of[dc][qc]);

    __syncthreads();   // all waves done reading before next stage overwrites
  }

  // ---- epilogue: l-reduce across g-groups, normalize, store ----
  #pragma unroll
  for (int qc = 0; qc < 2; qc++){
    int qn = qn_[qc];
    if (qn >= 1032) continue;
    float lt = lrun[qc];
    lt += __shfl_xor(lt, 16);
    lt += __shfl_xor(lt, 32);
    float inv = 1.0f / lt;
    unsigned short* dst = ao + ((int64_t)(b * 1032 + qn)) * 768 + head * 64;
    #pragma unroll
    for (int dc = 0; dc < 4; dc++){
      us4v pk = { f2bf(of[dc][qc][0] * inv), f2bf(of[dc][qc][1] * inv),
                  f2bf(of[dc][qc][2] * inv), f2bf(of[dc][qc][3] * inv) };
      *(us4v*)(dst + dc * 16 + g * 4) = pk;
    }
  }
}

extern "C" void kernel_launch(void* const* d_in, const int* in_sizes, int n_in,
                              void* d_out, int out_size, void* d_ws, size_t ws_size,
                              hipStream_t stream)
{
  const float* x   = (const float*)d_in[0];
  const float* vp  = (const float*)d_in[1];
  const float* qw  = (const float*)d_in[2];
  const float* qbb = (const float*)d_in[3];
  const float* pw  = (const float*)d_in[4];
  const float* pb  = (const float*)d_in[5];
  const float* rph = (const float*)d_in[6];
  const float* rpw = (const float*)d_in[7];
  float* out = (float*)d_out;

  char* ws = (char*)d_ws;
  size_t off = 0;
  auto alloc = [&](size_t bytes) -> void* {
    void* p = ws + off;
    off = (off + bytes + 255) & ~(size_t)255;
    return p;
  };
  unsigned short* xs   = (unsigned short*)alloc((size_t)8256 * 768 * 2);
  unsigned short* Wt   = (unsigned short*)alloc((size_t)2304 * 768 * 2);
  unsigned short* Pt   = (unsigned short*)alloc((size_t)768 * 768 * 2);
  unsigned short* qbuf = (unsigned short*)alloc((size_t)96 * 1032 * 64 * 2);
  unsigned short* kbuf = (unsigned short*)alloc((size_t)96 * 1032 * 64 * 2 + 4096);
  unsigned short* vtb  = (unsigned short*)alloc((size_t)96 * 64 * 1032 * 2 + 4096);
  float* relh = (float*)alloc((size_t)96 * 32 * 1024 * 4);
  float* relw = (float*)alloc((size_t)96 * 1024 * 32 * 4);
  unsigned short* ao = xs;  // xs dead after QKV GEMM; reuse for attention output

  k_prep<<<8496, 256, 0, stream>>>(x, vp, qw, pw, xs, Wt, Pt);
  k_gemm<0, 128><<<dim3(18, 65), 256, 0, stream>>>(xs, Wt, qbb, 8256, 2304, 768,
                                                   qbuf, kbuf, vtb, nullptr);
  k_rel<<<6144, 64, 0, stream>>>(qbuf, rph, rpw, relh, relw);
  k_attn<<<864, 256, 0, stream>>>(qbuf, kbuf, vtb, relh, relw, ao);
  k_gemm<1, 64><<<dim3(12, 65), 256, 0, stream>>>(ao, Pt, pb, 8256, 768, 768,
                                                  nullptr, nullptr, nullptr, out);
}